// Round 15
// baseline (234.873 us; speedup 1.0000x reference)
//
#include <hip/hip_runtime.h>

#define B_ 8
#define Q_ 64
#define K_ 512
#define NU_ 512
#define D_ 512

typedef __attribute__((ext_vector_type(8))) _Float16 half8;
typedef __attribute__((ext_vector_type(16))) float floatx16;

#define C2F 2.8853900817779268f  // 2*log2(e)

// ws float region
#define WS_V 0                   // v[0..511], vtot at [512]
#define WS_EQ 640                // Eq: 8*64*512 f32
#define WS_EK (640 + 262144)     // Ek: 8*512*512 f32
#define WS_FLOATS (WS_EK + 2097152)
// ws half region (after floats)
#define ACVT_ELEMS 2359296  // 8 b * 576 rows (512 keys + 64 query) * 512
#define W_ELEMS 262144      // 512*512
#define KT_ELEMS 2097152    // keysT: 8 b * 512 d * 512 k
#define SH_ELEMS 262144     // Sh: 8 b * 64 q * 512 k

#define GLD16(gp, lp)                                                         \
  __builtin_amdgcn_global_load_lds(                                           \
      (const __attribute__((address_space(1))) void*)(gp),                    \
      (__attribute__((address_space(3))) void*)(lp), 16, 0, 0)

// 16B-block swizzle (involution): dst block swz(B,row) holds logical block B.
__device__ __forceinline__ int swz(int bb, int row) {
  return (bb & 56) | ((bb ^ row) & 7);
}

// ---------------------------------------------------------------------------
// Kernel 1: f32 -> f16 convert into PRE-SWIZZLED per-batch layout + keysT
// transpose + v. Blocks: A [0,1152), Wk [1152,1280), Wq [1280,1408),
// keysT-transpose [1408,1920), v = 1920. All A/T blocks XCD-pinned (b=bid&7).
// ---------------------------------------------------------------------------
__global__ __launch_bounds__(256) void convert_kernel(
    const float* __restrict__ query, const float* __restrict__ keys,
    const float* __restrict__ Wq, const float* __restrict__ Wk,
    const float* __restrict__ la, const float* __restrict__ scalar,
    _Float16* __restrict__ Acvt, _Float16* __restrict__ Wkcvt,
    _Float16* __restrict__ Wqcvt, _Float16* __restrict__ keysT,
    float* __restrict__ v) {
  int bid = blockIdx.x;
  int t = threadIdx.x;
  __shared__ float red[4], red2[4];
  __shared__ _Float16 sT[64][72];
  if (bid == 1920) {  // v block
    float x0 = la[t], x1 = la[t + 256];
    float ss = x0 * x0 + x1 * x1;
#pragma unroll
    for (int o = 1; o < 64; o <<= 1) ss += __shfl_xor(ss, o, 64);
    int wave = t >> 6, lane = t & 63;
    if (lane == 0) red[wave] = ss;
    __syncthreads();
    float tot = red[0] + red[1] + red[2] + red[3];
    float sc = rsqrtf(tot) * scalar[0];
    float v0 = x0 * sc, v1 = x1 * sc;
    v[t] = v0;
    v[t + 256] = v1;
    float sv = v0 + v1;
#pragma unroll
    for (int o = 1; o < 64; o <<= 1) sv += __shfl_xor(sv, o, 64);
    if (lane == 0) red2[wave] = sv;
    __syncthreads();
    if (t == 0) v[512] = red2[0] + red2[1] + red2[2] + red2[3];
    return;
  }
  if (bid >= 1408) {  // keysT transpose blocks
    int j = bid - 1408;  // [0,512)
    int b = j & 7;
    int tile = j >> 3;  // [0,64)
    int kt = tile & 7, dtt = tile >> 3;
    int k0 = kt * 64, d0 = dtt * 64;
    const float* kb_ = keys + ((size_t)b * 512 + k0) * 512 + d0;
    int rl = t >> 4;        // 0..15
    int cl = (t & 15) * 4;  // 0..60
#pragma unroll
    for (int p = 0; p < 4; p++) {
      float4 x =
          *reinterpret_cast<const float4*>(kb_ + (size_t)(rl + 16 * p) * 512 + cl);
      sT[cl + 0][rl + 16 * p] = (_Float16)x.x;
      sT[cl + 1][rl + 16 * p] = (_Float16)x.y;
      sT[cl + 2][rl + 16 * p] = (_Float16)x.z;
      sT[cl + 3][rl + 16 * p] = (_Float16)x.w;
    }
    __syncthreads();
    int drl = t >> 2;  // 0..63
    int drow = d0 + drl;
#pragma unroll
    for (int e = 0; e < 2; e++) {
      int kb2 = (t & 3) * 2 + e;  // local 16B block 0..7
      int bb = (k0 >> 3) + kb2;   // global k block
      int sb = swz(bb, drow);
      half8 o = *reinterpret_cast<const half8*>(&sT[drl][kb2 * 8]);
      *reinterpret_cast<half8*>(keysT + ((size_t)b * 512 + drow) * 512 + sb * 8) = o;
    }
    return;
  }
  const float* src;
  _Float16* dst;
  int r, bb = t & 63;
  if (bid < 1152) {  // A: XCD-pinned per batch
    int b = bid & 7;
    int i = bid >> 3;
    r = i * 4 + (t >> 6);  // local row [0,576)
    src = (r < 512) ? keys + ((size_t)b * 512 + r) * 512
                    : query + ((size_t)b * 64 + (r - 512)) * 512;
    dst = Acvt + ((size_t)b * 576 + r) * 512;
  } else if (bid < 1280) {
    int j = bid - 1152;
    r = j * 4 + (t >> 6);
    src = Wk + (size_t)r * 512;
    dst = Wkcvt + (size_t)r * 512;
  } else {
    int j = bid - 1280;
    r = j * 4 + (t >> 6);
    src = Wq + (size_t)r * 512;
    dst = Wqcvt + (size_t)r * 512;
  }
  int scol = swz(bb, r) * 8;
  float4 x0 = *reinterpret_cast<const float4*>(src + scol);
  float4 x1 = *reinterpret_cast<const float4*>(src + scol + 4);
  half8 o = {(_Float16)x0.x, (_Float16)x0.y, (_Float16)x0.z, (_Float16)x0.w,
             (_Float16)x1.x, (_Float16)x1.y, (_Float16)x1.z, (_Float16)x1.w};
  *reinterpret_cast<half8*>(dst + bb * 8) = o;
}

// ---------------------------------------------------------------------------
// Kernel 2: MFMA projection (unchanged from round 12). XCD-pinned.
// ---------------------------------------------------------------------------
__global__ __launch_bounds__(256) void mfma_proj_kernel(
    const _Float16* __restrict__ Acvt, const _Float16* __restrict__ Wkcvt,
    const _Float16* __restrict__ Wqcvt, const float* __restrict__ bias,
    float* __restrict__ Ek, float* __restrict__ Eq) {
  __shared__ _Float16 sA[2][64][64];
  __shared__ _Float16 sW[2][64][64];
  int lid = blockIdx.x;  // [0,576)
  int b = lid & 7;
  int rr = lid >> 3;
  int mtb = rr % 9;
  int nt = rr / 9;
  int n0 = nt * 64;
  bool isQ = (mtb == 8);
  const _Float16* Wcvt = isQ ? Wqcvt : Wkcvt;
  size_t mrowbase = (size_t)b * 576 + (size_t)mtb * 64;
  int t = threadIdx.x;
  int wave = t >> 6, lane = t & 63;
  int mw = (wave >> 1) * 32, nw = (wave & 1) * 32;
  int lr = lane & 31, g = lane >> 5;
  int arow = mw + lr, wrow = nw + lr;
  int lrow = lane >> 3, lblk = lane & 7;
  const _Float16* gAbase = Acvt + (mrowbase + wave * 16 + lrow) * 512 + lblk * 8;
  const _Float16* gWbase =
      Wcvt + ((size_t)(n0 + wave * 16 + lrow)) * 512 + lblk * 8;

  floatx16 acc;
#pragma unroll
  for (int i = 0; i < 16; i++) acc[i] = 0.f;

#define STAGE(kt, sel)                                                        \
  {                                                                           \
    int koff = (kt)*64;                                                       \
    GLD16(gAbase + koff, &sA[sel][wave * 16][0]);                             \
    GLD16(gAbase + koff + 8 * 512, &sA[sel][wave * 16 + 8][0]);               \
    GLD16(gWbase + koff, &sW[sel][wave * 16][0]);                             \
    GLD16(gWbase + koff + 8 * 512, &sW[sel][wave * 16 + 8][0]);               \
  }

  STAGE(0, 0);
  for (int kt = 0; kt < 8; kt++) {
    __syncthreads();
    if (kt < 7) STAGE(kt + 1, (kt + 1) & 1);
    int sel = kt & 1;
#pragma unroll
    for (int i = 0; i < 4; i++) {
      int ablk = (((2 * i + g) ^ arow) & 7) * 8 + ((2 * i + g) & ~7) * 8;
      int wblk = (((2 * i + g) ^ wrow) & 7) * 8 + ((2 * i + g) & ~7) * 8;
      half8 af = *reinterpret_cast<const half8*>(&sA[sel][arow][ablk]);
      half8 wf = *reinterpret_cast<const half8*>(&sW[sel][wrow][wblk]);
      acc = __builtin_amdgcn_mfma_f32_32x32x16_f16(af, wf, acc, 0, 0, 0);
    }
  }
#undef STAGE
  int col = n0 + nw + lr;
  float bv = isQ ? bias[col] : 0.f;
#pragma unroll
  for (int r = 0; r < 16; r++) {
    int lrow_out = mtb * 64 + mw + (r & 3) + 8 * (r >> 2) + 4 * g;
    float e = __builtin_amdgcn_exp2f((acc[r] + bv) * C2F);
    if (isQ)
      Eq[((size_t)b * 64 + (lrow_out - 512)) * NU_ + col] = e;
    else
      Ek[((size_t)b * 512 + lrow_out) * NU_ + col] = e;
  }
}

// ---------------------------------------------------------------------------
// Kernel 3: scores with 2-k register blocking (each thread: 2 k, 8 q, 16 u).
// One sEq read feeds 2 k-rows -> LDS bytes halved vs R14. 4-term rational
// combine (1 rcp per 4 u-terms per k). Writes Sh f16 pre-swizzled.
// S[q,k] = vtot - 2 * sum_u v[u] / (1 + Eq[q,u]*Ek[k,u])
// ---------------------------------------------------------------------------
__global__ __launch_bounds__(256, 8) void scores_kernel(
    const float* __restrict__ Eq, const float* __restrict__ Ek,
    const float* __restrict__ v, _Float16* __restrict__ Sh) {
  __shared__ __align__(16) float sEq[8][NU_];
  __shared__ __align__(16) float sV[NU_];
  __shared__ float sRed[2][4][8][2];
  int lid = blockIdx.x;
  int b = lid & 7;
  int rrr = lid >> 3;
  int qt = rrr & 7, kt = rrr >> 3;
  int q0 = qt * 8, k0 = kt * 16;
  int t = threadIdx.x;
  const float4* eqsrc =
      reinterpret_cast<const float4*>(Eq + ((size_t)b * Q_ + q0) * NU_);
#pragma unroll
  for (int i = 0; i < 4; i++)
    reinterpret_cast<float4*>(&sEq[0][0])[t + 256 * i] = eqsrc[t + 256 * i];
  if (t < 128)
    reinterpret_cast<float4*>(sV)[t] = reinterpret_cast<const float4*>(v)[t];
  float vtot = v[512];
  __syncthreads();

  int wave = t >> 6, lane = t & 63;
  int uw = wave >> 1, kw = wave & 1;
  int klane = lane >> 4, ulane = lane & 15;
  int k = k0 + kw * 8 + klane * 2;
  const float* ekr0 = Ek + ((size_t)b * K_ + k) * NU_;
  const float* ekr1 = ekr0 + NU_;
  float acc0[8] = {}, acc1[8] = {};
#pragma unroll
  for (int j = 0; j < 4; j++) {
    int u = uw * 256 + ulane * 4 + 64 * j;
    float4 e0 = *reinterpret_cast<const float4*>(ekr0 + u);
    float4 e1 = *reinterpret_cast<const float4*>(ekr1 + u);
    float4 v4 = *reinterpret_cast<const float4*>(&sV[u]);
#pragma unroll
    for (int qq = 0; qq < 8; qq++) {
      float4 q4 = *reinterpret_cast<const float4*>(&sEq[qq][u]);
      // k row 0
      {
        float p0 = fmaf(q4.x, e0.x, 1.f);
        float p1 = fmaf(q4.y, e0.y, 1.f);
        float p2 = fmaf(q4.z, e0.z, 1.f);
        float p3 = fmaf(q4.w, e0.w, 1.f);
        float n01 = fmaf(v4.x, p1, v4.y * p0);
        float n23 = fmaf(v4.z, p3, v4.w * p2);
        float p01 = p0 * p1, p23 = p2 * p3;
        float num = fmaf(n01, p23, n23 * p01);
        acc0[qq] = fmaf(num, __builtin_amdgcn_rcpf(p01 * p23), acc0[qq]);
      }
      // k row 1
      {
        float p0 = fmaf(q4.x, e1.x, 1.f);
        float p1 = fmaf(q4.y, e1.y, 1.f);
        float p2 = fmaf(q4.z, e1.z, 1.f);
        float p3 = fmaf(q4.w, e1.w, 1.f);
        float n01 = fmaf(v4.x, p1, v4.y * p0);
        float n23 = fmaf(v4.z, p3, v4.w * p2);
        float p01 = p0 * p1, p23 = p2 * p3;
        float num = fmaf(n01, p23, n23 * p01);
        acc1[qq] = fmaf(num, __builtin_amdgcn_rcpf(p01 * p23), acc1[qq]);
      }
    }
  }
  // reduce over the 16 ulane lanes (bits 0..3)
#pragma unroll
  for (int qq = 0; qq < 8; qq++) {
    acc0[qq] += __shfl_xor(acc0[qq], 1, 64);
    acc0[qq] += __shfl_xor(acc0[qq], 2, 64);
    acc0[qq] += __shfl_xor(acc0[qq], 4, 64);
    acc0[qq] += __shfl_xor(acc0[qq], 8, 64);
    acc1[qq] += __shfl_xor(acc1[qq], 1, 64);
    acc1[qq] += __shfl_xor(acc1[qq], 2, 64);
    acc1[qq] += __shfl_xor(acc1[qq], 4, 64);
    acc1[qq] += __shfl_xor(acc1[qq], 8, 64);
  }
  if (uw == 1 && ulane == 0) {
#pragma unroll
    for (int qq = 0; qq < 8; qq++) {
      sRed[kw][klane][qq][0] = acc0[qq];
      sRed[kw][klane][qq][1] = acc1[qq];
    }
  }
  __syncthreads();
  if (uw == 0 && ulane == 0) {
#pragma unroll
    for (int qq = 0; qq < 8; qq++) {
      float a0 = acc0[qq] + sRed[kw][klane][qq][0];
      float a1 = acc1[qq] + sRed[kw][klane][qq][1];
      float s0 = fmaf(-2.f, a0, vtot);
      float s1 = fmaf(-2.f, a1, vtot);
      int row = q0 + qq;
      int sb = swz(k >> 3, row);
      _Float16* dst = Sh + ((size_t)b * 64 + row) * 512 + sb * 8 + (k & 7);
      dst[0] = (_Float16)s0;
      dst[1] = (_Float16)s1;
    }
  }
}

// ---------------------------------------------------------------------------
// Kernel 4: ctx via MFMA (blocks 0..63) + softmax (blocks 64..127).
// (unchanged from round 12)
// ---------------------------------------------------------------------------
__global__ __launch_bounds__(256) void ctxsm_kernel(
    const _Float16* __restrict__ Sh, const _Float16* __restrict__ keysT,
    float* __restrict__ ctx, float* __restrict__ smx) {
  __shared__ _Float16 sA[2][64][64];
  __shared__ _Float16 sW[2][64][64];
  int bid = blockIdx.x;
  int t = threadIdx.x;
  if (bid >= 64) {  // ---- softmax blocks ----
    int idx = bid - 64;
    int b = idx & 7, qt = idx >> 3;
    int q = qt * 8 + (t >> 5), lg = t & 31;
    const _Float16* srow = Sh + ((size_t)b * 64 + q) * 512;
    float sv[16];
#pragma unroll
    for (int ii = 0; ii < 16; ii++) {
      int kk = lg + ii * 32;
      int sb = swz(kk >> 3, q);
      sv[ii] = (float)srow[sb * 8 + (kk & 7)];
    }
    float m = sv[0];
#pragma unroll
    for (int ii = 1; ii < 16; ii++) m = fmaxf(m, sv[ii]);
#pragma unroll
    for (int o = 1; o < 32; o <<= 1) m = fmaxf(m, __shfl_xor(m, o, 64));
    const float L2E = 1.4426950408889634f;
    float e[16], sum = 0.f;
#pragma unroll
    for (int ii = 0; ii < 16; ii++) {
      e[ii] = __builtin_amdgcn_exp2f((sv[ii] - m) * L2E);
      sum += e[ii];
    }
#pragma unroll
    for (int o = 1; o < 32; o <<= 1) sum += __shfl_xor(sum, o, 64);
    float inv = 1.f / sum;
    float* dst = smx + ((size_t)b * 64 + q) * 512;
#pragma unroll
    for (int ii = 0; ii < 16; ii++) dst[lg + ii * 32] = e[ii] * inv;
    return;
  }
  // ---- MFMA ctx blocks ----
  int b = bid & 7, nt = bid >> 3;
  int n0 = nt * 64;
  int wave = t >> 6, lane = t & 63;
  int mw = (wave >> 1) * 32, nw = (wave & 1) * 32;
  int lr = lane & 31, g = lane >> 5;
  int arow = mw + lr, wrow = nw + lr;
  int lrow = lane >> 3, lblk = lane & 7;
  const _Float16* gAbase =
      Sh + ((size_t)b * 64 + wave * 16 + lrow) * 512 + lblk * 8;
  const _Float16* gWbase =
      keysT + ((size_t)b * 512 + n0 + wave * 16 + lrow) * 512 + lblk * 8;

  floatx16 acc;
#pragma unroll
  for (int i = 0; i < 16; i++) acc[i] = 0.f;

#define STAGE(kt, sel)                                                        \
  {                                                                           \
    int koff = (kt)*64;                                                       \
    GLD16(gAbase + koff, &sA[sel][wave * 16][0]);                             \
    GLD16(gAbase + koff + 8 * 512, &sA[sel][wave * 16 + 8][0]);               \
    GLD16(gWbase + koff, &sW[sel][wave * 16][0]);                             \
    GLD16(gWbase + koff + 8 * 512, &sW[sel][wave * 16 + 8][0]);               \
  }

  STAGE(0, 0);
  for (int kt = 0; kt < 8; kt++) {
    __syncthreads();
    if (kt < 7) STAGE(kt + 1, (kt + 1) & 1);
    int sel = kt & 1;
#pragma unroll
    for (int i = 0; i < 4; i++) {
      int ablk = (((2 * i + g) ^ arow) & 7) * 8 + ((2 * i + g) & ~7) * 8;
      int wblk = (((2 * i + g) ^ wrow) & 7) * 8 + ((2 * i + g) & ~7) * 8;
      half8 af = *reinterpret_cast<const half8*>(&sA[sel][arow][ablk]);
      half8 wf = *reinterpret_cast<const half8*>(&sW[sel][wrow][wblk]);
      acc = __builtin_amdgcn_mfma_f32_32x32x16_f16(af, wf, acc, 0, 0, 0);
    }
  }
#undef STAGE
  int col = n0 + nw + lr;
#pragma unroll
  for (int r = 0; r < 16; r++) {
    int row = mw + (r & 3) + 8 * (r >> 2) + 4 * g;
    ctx[((size_t)b * 64 + row) * 512 + col] = acc[r];
  }
}

// ---------------------------------------------------------------------------
extern "C" void kernel_launch(void* const* d_in, const int* in_sizes, int n_in,
                              void* d_out, int out_size, void* d_ws,
                              size_t ws_size, hipStream_t stream) {
  const float* query = (const float*)d_in[0];
  const float* keys = (const float*)d_in[1];
  const float* Wq = (const float*)d_in[2];
  const float* Wk = (const float*)d_in[3];
  const float* la = (const float*)d_in[4];
  const float* nscalar = (const float*)d_in[5];
  const float* nbias = (const float*)d_in[6];

  float* out = (float*)d_out;
  float* ctx = out;
  float* smx = out + (size_t)B_ * Q_ * D_;

  float* ws = (float*)d_ws;
  float* v = ws + WS_V;
  float* Eq = ws + WS_EQ;
  float* Ek = ws + WS_EK;
  _Float16* Acvt = (_Float16*)(ws + WS_FLOATS);
  _Float16* Wkcvt = Acvt + ACVT_ELEMS;
  _Float16* Wqcvt = Wkcvt + W_ELEMS;
  _Float16* keysT = Wqcvt + W_ELEMS;
  _Float16* Sh = keysT + KT_ELEMS;

  convert_kernel<<<1921, 256, 0, stream>>>(query, keys, Wq, Wk, la, nscalar,
                                           Acvt, Wkcvt, Wqcvt, keysT, v);
  mfma_proj_kernel<<<576, 256, 0, stream>>>(Acvt, Wkcvt, Wqcvt, nbias, Ek, Eq);
  scores_kernel<<<2048, 256, 0, stream>>>(Eq, Ek, v, Sh);
  ctxsm_kernel<<<128, 256, 0, stream>>>(Sh, keysT, ctx, smx);
}

// Round 16
// 126.550 us; speedup vs baseline: 1.8560x; 1.8560x over previous
//
#include <hip/hip_runtime.h>

#define B_ 8
#define Q_ 64
#define K_ 512
#define NU_ 512
#define D_ 512

typedef __attribute__((ext_vector_type(8))) _Float16 half8;
typedef __attribute__((ext_vector_type(16))) float floatx16;

#define C2F 2.8853900817779268f  // 2*log2(e)

// ws float region
#define WS_V 0                   // v[0..511], vtot at [512]
#define WS_EQ 640                // Eq: 8*64*512 f32
#define WS_EK (640 + 262144)     // Ek: 8*512*512 f32
#define WS_FLOATS (WS_EK + 2097152)
// ws half region (after floats)
#define ACVT_ELEMS 2359296  // 8 b * 576 rows (512 keys + 64 query) * 512
#define W_ELEMS 262144      // 512*512
#define KT_ELEMS 2097152    // keysT: 8 b * 512 d * 512 k
#define SH_ELEMS 262144     // Sh: 8 b * 64 q * 512 k

#define GLD16(gp, lp)                                                         \
  __builtin_amdgcn_global_load_lds(                                           \
      (const __attribute__((address_space(1))) void*)(gp),                    \
      (__attribute__((address_space(3))) void*)(lp), 16, 0, 0)

// 16B-block swizzle (involution): dst block swz(B,row) holds logical block B.
__device__ __forceinline__ int swz(int bb, int row) {
  return (bb & 56) | ((bb ^ row) & 7);
}

// ---------------------------------------------------------------------------
// Kernel 1: f32 -> f16 convert into PRE-SWIZZLED per-batch layout + keysT
// transpose + v. Blocks: A [0,1152), Wk [1152,1280), Wq [1280,1408),
// keysT-transpose [1408,1920), v = 1920. All A/T blocks XCD-pinned (b=bid&7).
// ---------------------------------------------------------------------------
__global__ __launch_bounds__(256) void convert_kernel(
    const float* __restrict__ query, const float* __restrict__ keys,
    const float* __restrict__ Wq, const float* __restrict__ Wk,
    const float* __restrict__ la, const float* __restrict__ scalar,
    _Float16* __restrict__ Acvt, _Float16* __restrict__ Wkcvt,
    _Float16* __restrict__ Wqcvt, _Float16* __restrict__ keysT,
    float* __restrict__ v) {
  int bid = blockIdx.x;
  int t = threadIdx.x;
  __shared__ float red[4], red2[4];
  __shared__ _Float16 sT[64][72];
  if (bid == 1920) {  // v block
    float x0 = la[t], x1 = la[t + 256];
    float ss = x0 * x0 + x1 * x1;
#pragma unroll
    for (int o = 1; o < 64; o <<= 1) ss += __shfl_xor(ss, o, 64);
    int wave = t >> 6, lane = t & 63;
    if (lane == 0) red[wave] = ss;
    __syncthreads();
    float tot = red[0] + red[1] + red[2] + red[3];
    float sc = rsqrtf(tot) * scalar[0];
    float v0 = x0 * sc, v1 = x1 * sc;
    v[t] = v0;
    v[t + 256] = v1;
    float sv = v0 + v1;
#pragma unroll
    for (int o = 1; o < 64; o <<= 1) sv += __shfl_xor(sv, o, 64);
    if (lane == 0) red2[wave] = sv;
    __syncthreads();
    if (t == 0) v[512] = red2[0] + red2[1] + red2[2] + red2[3];
    return;
  }
  if (bid >= 1408) {  // keysT transpose blocks
    int j = bid - 1408;  // [0,512)
    int b = j & 7;
    int tile = j >> 3;  // [0,64)
    int kt = tile & 7, dtt = tile >> 3;
    int k0 = kt * 64, d0 = dtt * 64;
    const float* kb_ = keys + ((size_t)b * 512 + k0) * 512 + d0;
    int rl = t >> 4;        // 0..15
    int cl = (t & 15) * 4;  // 0..60
#pragma unroll
    for (int p = 0; p < 4; p++) {
      float4 x =
          *reinterpret_cast<const float4*>(kb_ + (size_t)(rl + 16 * p) * 512 + cl);
      sT[cl + 0][rl + 16 * p] = (_Float16)x.x;
      sT[cl + 1][rl + 16 * p] = (_Float16)x.y;
      sT[cl + 2][rl + 16 * p] = (_Float16)x.z;
      sT[cl + 3][rl + 16 * p] = (_Float16)x.w;
    }
    __syncthreads();
    int drl = t >> 2;  // 0..63
    int drow = d0 + drl;
#pragma unroll
    for (int e = 0; e < 2; e++) {
      int kb2 = (t & 3) * 2 + e;  // local 16B block 0..7
      int bb = (k0 >> 3) + kb2;   // global k block
      int sb = swz(bb, drow);
      half8 o = *reinterpret_cast<const half8*>(&sT[drl][kb2 * 8]);
      *reinterpret_cast<half8*>(keysT + ((size_t)b * 512 + drow) * 512 + sb * 8) = o;
    }
    return;
  }
  const float* src;
  _Float16* dst;
  int r, bb = t & 63;
  if (bid < 1152) {  // A: XCD-pinned per batch
    int b = bid & 7;
    int i = bid >> 3;
    r = i * 4 + (t >> 6);  // local row [0,576)
    src = (r < 512) ? keys + ((size_t)b * 512 + r) * 512
                    : query + ((size_t)b * 64 + (r - 512)) * 512;
    dst = Acvt + ((size_t)b * 576 + r) * 512;
  } else if (bid < 1280) {
    int j = bid - 1152;
    r = j * 4 + (t >> 6);
    src = Wk + (size_t)r * 512;
    dst = Wkcvt + (size_t)r * 512;
  } else {
    int j = bid - 1280;
    r = j * 4 + (t >> 6);
    src = Wq + (size_t)r * 512;
    dst = Wqcvt + (size_t)r * 512;
  }
  int scol = swz(bb, r) * 8;
  float4 x0 = *reinterpret_cast<const float4*>(src + scol);
  float4 x1 = *reinterpret_cast<const float4*>(src + scol + 4);
  half8 o = {(_Float16)x0.x, (_Float16)x0.y, (_Float16)x0.z, (_Float16)x0.w,
             (_Float16)x1.x, (_Float16)x1.y, (_Float16)x1.z, (_Float16)x1.w};
  *reinterpret_cast<half8*>(dst + bb * 8) = o;
}

// ---------------------------------------------------------------------------
// Kernel 2: MFMA projection (unchanged from round 12). XCD-pinned.
// ---------------------------------------------------------------------------
__global__ __launch_bounds__(256) void mfma_proj_kernel(
    const _Float16* __restrict__ Acvt, const _Float16* __restrict__ Wkcvt,
    const _Float16* __restrict__ Wqcvt, const float* __restrict__ bias,
    float* __restrict__ Ek, float* __restrict__ Eq) {
  __shared__ _Float16 sA[2][64][64];
  __shared__ _Float16 sW[2][64][64];
  int lid = blockIdx.x;  // [0,576)
  int b = lid & 7;
  int rr = lid >> 3;
  int mtb = rr % 9;
  int nt = rr / 9;
  int n0 = nt * 64;
  bool isQ = (mtb == 8);
  const _Float16* Wcvt = isQ ? Wqcvt : Wkcvt;
  size_t mrowbase = (size_t)b * 576 + (size_t)mtb * 64;
  int t = threadIdx.x;
  int wave = t >> 6, lane = t & 63;
  int mw = (wave >> 1) * 32, nw = (wave & 1) * 32;
  int lr = lane & 31, g = lane >> 5;
  int arow = mw + lr, wrow = nw + lr;
  int lrow = lane >> 3, lblk = lane & 7;
  const _Float16* gAbase = Acvt + (mrowbase + wave * 16 + lrow) * 512 + lblk * 8;
  const _Float16* gWbase =
      Wcvt + ((size_t)(n0 + wave * 16 + lrow)) * 512 + lblk * 8;

  floatx16 acc;
#pragma unroll
  for (int i = 0; i < 16; i++) acc[i] = 0.f;

#define STAGE(kt, sel)                                                        \
  {                                                                           \
    int koff = (kt)*64;                                                       \
    GLD16(gAbase + koff, &sA[sel][wave * 16][0]);                             \
    GLD16(gAbase + koff + 8 * 512, &sA[sel][wave * 16 + 8][0]);               \
    GLD16(gWbase + koff, &sW[sel][wave * 16][0]);                             \
    GLD16(gWbase + koff + 8 * 512, &sW[sel][wave * 16 + 8][0]);               \
  }

  STAGE(0, 0);
  for (int kt = 0; kt < 8; kt++) {
    __syncthreads();
    if (kt < 7) STAGE(kt + 1, (kt + 1) & 1);
    int sel = kt & 1;
#pragma unroll
    for (int i = 0; i < 4; i++) {
      int ablk = (((2 * i + g) ^ arow) & 7) * 8 + ((2 * i + g) & ~7) * 8;
      int wblk = (((2 * i + g) ^ wrow) & 7) * 8 + ((2 * i + g) & ~7) * 8;
      half8 af = *reinterpret_cast<const half8*>(&sA[sel][arow][ablk]);
      half8 wf = *reinterpret_cast<const half8*>(&sW[sel][wrow][wblk]);
      acc = __builtin_amdgcn_mfma_f32_32x32x16_f16(af, wf, acc, 0, 0, 0);
    }
  }
#undef STAGE
  int col = n0 + nw + lr;
  float bv = isQ ? bias[col] : 0.f;
#pragma unroll
  for (int r = 0; r < 16; r++) {
    int lrow_out = mtb * 64 + mw + (r & 3) + 8 * (r >> 2) + 4 * g;
    float e = __builtin_amdgcn_exp2f((acc[r] + bv) * C2F);
    if (isQ)
      Eq[((size_t)b * 64 + (lrow_out - 512)) * NU_ + col] = e;
    else
      Ek[((size_t)b * 512 + lrow_out) * NU_ + col] = e;
  }
}

// ---------------------------------------------------------------------------
// Kernel 3: scores with 2-k register blocking (each thread: 2 k, 8 q, 16 u).
// launch_bounds(256,4): 128-VGPR budget so the 16-acc live set does NOT
// spill (R15's (256,8)=64-VGPR cap spilled -> 457 MB scratch writes).
// One sEq read feeds 2 k-rows -> LDS bytes halved vs R14.
// S[q,k] = vtot - 2 * sum_u v[u] / (1 + Eq[q,u]*Ek[k,u])
// ---------------------------------------------------------------------------
__global__ __launch_bounds__(256, 4) void scores_kernel(
    const float* __restrict__ Eq, const float* __restrict__ Ek,
    const float* __restrict__ v, _Float16* __restrict__ Sh) {
  __shared__ __align__(16) float sEq[8][NU_];
  __shared__ __align__(16) float sV[NU_];
  __shared__ float sRed[2][4][8][2];
  int lid = blockIdx.x;
  int b = lid & 7;
  int rrr = lid >> 3;
  int qt = rrr & 7, kt = rrr >> 3;
  int q0 = qt * 8, k0 = kt * 16;
  int t = threadIdx.x;
  const float4* eqsrc =
      reinterpret_cast<const float4*>(Eq + ((size_t)b * Q_ + q0) * NU_);
#pragma unroll
  for (int i = 0; i < 4; i++)
    reinterpret_cast<float4*>(&sEq[0][0])[t + 256 * i] = eqsrc[t + 256 * i];
  if (t < 128)
    reinterpret_cast<float4*>(sV)[t] = reinterpret_cast<const float4*>(v)[t];
  float vtot = v[512];
  __syncthreads();

  int wave = t >> 6, lane = t & 63;
  int uw = wave >> 1, kw = wave & 1;
  int klane = lane >> 4, ulane = lane & 15;
  int k = k0 + kw * 8 + klane * 2;
  const float* ekr0 = Ek + ((size_t)b * K_ + k) * NU_;
  const float* ekr1 = ekr0 + NU_;
  float acc0[8] = {}, acc1[8] = {};
#pragma unroll
  for (int j = 0; j < 4; j++) {
    int u = uw * 256 + ulane * 4 + 64 * j;
    float4 e0 = *reinterpret_cast<const float4*>(ekr0 + u);
    float4 e1 = *reinterpret_cast<const float4*>(ekr1 + u);
    float4 v4 = *reinterpret_cast<const float4*>(&sV[u]);
#pragma unroll
    for (int qq = 0; qq < 8; qq++) {
      float4 q4 = *reinterpret_cast<const float4*>(&sEq[qq][u]);
      // k row 0
      {
        float p0 = fmaf(q4.x, e0.x, 1.f);
        float p1 = fmaf(q4.y, e0.y, 1.f);
        float p2 = fmaf(q4.z, e0.z, 1.f);
        float p3 = fmaf(q4.w, e0.w, 1.f);
        float n01 = fmaf(v4.x, p1, v4.y * p0);
        float n23 = fmaf(v4.z, p3, v4.w * p2);
        float p01 = p0 * p1, p23 = p2 * p3;
        float num = fmaf(n01, p23, n23 * p01);
        acc0[qq] = fmaf(num, __builtin_amdgcn_rcpf(p01 * p23), acc0[qq]);
      }
      // k row 1
      {
        float p0 = fmaf(q4.x, e1.x, 1.f);
        float p1 = fmaf(q4.y, e1.y, 1.f);
        float p2 = fmaf(q4.z, e1.z, 1.f);
        float p3 = fmaf(q4.w, e1.w, 1.f);
        float n01 = fmaf(v4.x, p1, v4.y * p0);
        float n23 = fmaf(v4.z, p3, v4.w * p2);
        float p01 = p0 * p1, p23 = p2 * p3;
        float num = fmaf(n01, p23, n23 * p01);
        acc1[qq] = fmaf(num, __builtin_amdgcn_rcpf(p01 * p23), acc1[qq]);
      }
    }
  }
  // reduce over the 16 ulane lanes (bits 0..3)
#pragma unroll
  for (int qq = 0; qq < 8; qq++) {
    acc0[qq] += __shfl_xor(acc0[qq], 1, 64);
    acc0[qq] += __shfl_xor(acc0[qq], 2, 64);
    acc0[qq] += __shfl_xor(acc0[qq], 4, 64);
    acc0[qq] += __shfl_xor(acc0[qq], 8, 64);
    acc1[qq] += __shfl_xor(acc1[qq], 1, 64);
    acc1[qq] += __shfl_xor(acc1[qq], 2, 64);
    acc1[qq] += __shfl_xor(acc1[qq], 4, 64);
    acc1[qq] += __shfl_xor(acc1[qq], 8, 64);
  }
  if (uw == 1 && ulane == 0) {
#pragma unroll
    for (int qq = 0; qq < 8; qq++) {
      sRed[kw][klane][qq][0] = acc0[qq];
      sRed[kw][klane][qq][1] = acc1[qq];
    }
  }
  __syncthreads();
  if (uw == 0 && ulane == 0) {
#pragma unroll
    for (int qq = 0; qq < 8; qq++) {
      float a0 = acc0[qq] + sRed[kw][klane][qq][0];
      float a1 = acc1[qq] + sRed[kw][klane][qq][1];
      float s0 = fmaf(-2.f, a0, vtot);
      float s1 = fmaf(-2.f, a1, vtot);
      int row = q0 + qq;
      int sb = swz(k >> 3, row);
      _Float16* dst = Sh + ((size_t)b * 64 + row) * 512 + sb * 8 + (k & 7);
      dst[0] = (_Float16)s0;
      dst[1] = (_Float16)s1;
    }
  }
}

// ---------------------------------------------------------------------------
// Kernel 4: ctx via MFMA (blocks 0..63) + softmax (blocks 64..127).
// (unchanged from round 12)
// ---------------------------------------------------------------------------
__global__ __launch_bounds__(256) void ctxsm_kernel(
    const _Float16* __restrict__ Sh, const _Float16* __restrict__ keysT,
    float* __restrict__ ctx, float* __restrict__ smx) {
  __shared__ _Float16 sA[2][64][64];
  __shared__ _Float16 sW[2][64][64];
  int bid = blockIdx.x;
  int t = threadIdx.x;
  if (bid >= 64) {  // ---- softmax blocks ----
    int idx = bid - 64;
    int b = idx & 7, qt = idx >> 3;
    int q = qt * 8 + (t >> 5), lg = t & 31;
    const _Float16* srow = Sh + ((size_t)b * 64 + q) * 512;
    float sv[16];
#pragma unroll
    for (int ii = 0; ii < 16; ii++) {
      int kk = lg + ii * 32;
      int sb = swz(kk >> 3, q);
      sv[ii] = (float)srow[sb * 8 + (kk & 7)];
    }
    float m = sv[0];
#pragma unroll
    for (int ii = 1; ii < 16; ii++) m = fmaxf(m, sv[ii]);
#pragma unroll
    for (int o = 1; o < 32; o <<= 1) m = fmaxf(m, __shfl_xor(m, o, 64));
    const float L2E = 1.4426950408889634f;
    float e[16], sum = 0.f;
#pragma unroll
    for (int ii = 0; ii < 16; ii++) {
      e[ii] = __builtin_amdgcn_exp2f((sv[ii] - m) * L2E);
      sum += e[ii];
    }
#pragma unroll
    for (int o = 1; o < 32; o <<= 1) sum += __shfl_xor(sum, o, 64);
    float inv = 1.f / sum;
    float* dst = smx + ((size_t)b * 64 + q) * 512;
#pragma unroll
    for (int ii = 0; ii < 16; ii++) dst[lg + ii * 32] = e[ii] * inv;
    return;
  }
  // ---- MFMA ctx blocks ----
  int b = bid & 7, nt = bid >> 3;
  int n0 = nt * 64;
  int wave = t >> 6, lane = t & 63;
  int mw = (wave >> 1) * 32, nw = (wave & 1) * 32;
  int lr = lane & 31, g = lane >> 5;
  int arow = mw + lr, wrow = nw + lr;
  int lrow = lane >> 3, lblk = lane & 7;
  const _Float16* gAbase =
      Sh + ((size_t)b * 64 + wave * 16 + lrow) * 512 + lblk * 8;
  const _Float16* gWbase =
      keysT + ((size_t)b * 512 + n0 + wave * 16 + lrow) * 512 + lblk * 8;

  floatx16 acc;
#pragma unroll
  for (int i = 0; i < 16; i++) acc[i] = 0.f;

#define STAGE(kt, sel)                                                        \
  {                                                                           \
    int koff = (kt)*64;                                                       \
    GLD16(gAbase + koff, &sA[sel][wave * 16][0]);                             \
    GLD16(gAbase + koff + 8 * 512, &sA[sel][wave * 16 + 8][0]);               \
    GLD16(gWbase + koff, &sW[sel][wave * 16][0]);                             \
    GLD16(gWbase + koff + 8 * 512, &sW[sel][wave * 16 + 8][0]);               \
  }

  STAGE(0, 0);
  for (int kt = 0; kt < 8; kt++) {
    __syncthreads();
    if (kt < 7) STAGE(kt + 1, (kt + 1) & 1);
    int sel = kt & 1;
#pragma unroll
    for (int i = 0; i < 4; i++) {
      int ablk = (((2 * i + g) ^ arow) & 7) * 8 + ((2 * i + g) & ~7) * 8;
      int wblk = (((2 * i + g) ^ wrow) & 7) * 8 + ((2 * i + g) & ~7) * 8;
      half8 af = *reinterpret_cast<const half8*>(&sA[sel][arow][ablk]);
      half8 wf = *reinterpret_cast<const half8*>(&sW[sel][wrow][wblk]);
      acc = __builtin_amdgcn_mfma_f32_32x32x16_f16(af, wf, acc, 0, 0, 0);
    }
  }
#undef STAGE
  int col = n0 + nw + lr;
#pragma unroll
  for (int r = 0; r < 16; r++) {
    int row = mw + (r & 3) + 8 * (r >> 2) + 4 * g;
    ctx[((size_t)b * 64 + row) * 512 + col] = acc[r];
  }
}

// ---------------------------------------------------------------------------
extern "C" void kernel_launch(void* const* d_in, const int* in_sizes, int n_in,
                              void* d_out, int out_size, void* d_ws,
                              size_t ws_size, hipStream_t stream) {
  const float* query = (const float*)d_in[0];
  const float* keys = (const float*)d_in[1];
  const float* Wq = (const float*)d_in[2];
  const float* Wk = (const float*)d_in[3];
  const float* la = (const float*)d_in[4];
  const float* nscalar = (const float*)d_in[5];
  const float* nbias = (const float*)d_in[6];

  float* out = (float*)d_out;
  float* ctx = out;
  float* smx = out + (size_t)B_ * Q_ * D_;

  float* ws = (float*)d_ws;
  float* v = ws + WS_V;
  float* Eq = ws + WS_EQ;
  float* Ek = ws + WS_EK;
  _Float16* Acvt = (_Float16*)(ws + WS_FLOATS);
  _Float16* Wkcvt = Acvt + ACVT_ELEMS;
  _Float16* Wqcvt = Wkcvt + W_ELEMS;
  _Float16* keysT = Wqcvt + W_ELEMS;
  _Float16* Sh = keysT + KT_ELEMS;

  convert_kernel<<<1921, 256, 0, stream>>>(query, keys, Wq, Wk, la, nscalar,
                                           Acvt, Wkcvt, Wqcvt, keysT, v);
  mfma_proj_kernel<<<576, 256, 0, stream>>>(Acvt, Wkcvt, Wqcvt, nbias, Ek, Eq);
  scores_kernel<<<2048, 256, 0, stream>>>(Eq, Ek, v, Sh);
  ctxsm_kernel<<<128, 256, 0, stream>>>(Sh, keysT, ctx, smx);
}

// Round 17
// 41.833 us; speedup vs baseline: 5.6146x; 3.0252x over previous
//
#include <hip/hip_runtime.h>

#define B_ 8
#define Q_ 64
#define K_ 512
#define NU_ 512
#define D_ 512

typedef __attribute__((ext_vector_type(8))) _Float16 half8;
typedef __attribute__((ext_vector_type(16))) float floatx16;

#define C2F 2.8853900817779268f  // 2*log2(e)

// ws float region
#define WS_V 0                   // v[0..511], vtot at [512]
#define WS_EQ 640                // Eq: 8*64*512 f32
#define WS_EK (640 + 262144)     // Ek: 8*512*512 f32
#define WS_FLOATS (WS_EK + 2097152)
// ws half region (after floats)
#define ACVT_ELEMS 2359296  // 8 b * 576 rows (512 keys + 64 query) * 512
#define W_ELEMS 262144      // 512*512
#define KT_ELEMS 2097152    // keysT: 8 b * 512 d * 512 k
#define SH_ELEMS 262144     // Sh: 8 b * 64 q * 512 k

#define GLD16(gp, lp)                                                         \
  __builtin_amdgcn_global_load_lds(                                           \
      (const __attribute__((address_space(1))) void*)(gp),                    \
      (__attribute__((address_space(3))) void*)(lp), 16, 0, 0)

// 16B-block swizzle (involution): dst block swz(B,row) holds logical block B.
__device__ __forceinline__ int swz(int bb, int row) {
  return (bb & 56) | ((bb ^ row) & 7);
}

// ---------------------------------------------------------------------------
// Kernel 1: f32 -> f16 convert into PRE-SWIZZLED per-batch layout + keysT
// transpose + v. Blocks: A [0,1152), Wk [1152,1280), Wq [1280,1408),
// keysT-transpose [1408,1920), v = 1920. All A/T blocks XCD-pinned (b=bid&7).
// ---------------------------------------------------------------------------
__global__ __launch_bounds__(256) void convert_kernel(
    const float* __restrict__ query, const float* __restrict__ keys,
    const float* __restrict__ Wq, const float* __restrict__ Wk,
    const float* __restrict__ la, const float* __restrict__ scalar,
    _Float16* __restrict__ Acvt, _Float16* __restrict__ Wkcvt,
    _Float16* __restrict__ Wqcvt, _Float16* __restrict__ keysT,
    float* __restrict__ v) {
  int bid = blockIdx.x;
  int t = threadIdx.x;
  __shared__ float red[4], red2[4];
  __shared__ _Float16 sT[64][72];
  if (bid == 1920) {  // v block
    float x0 = la[t], x1 = la[t + 256];
    float ss = x0 * x0 + x1 * x1;
#pragma unroll
    for (int o = 1; o < 64; o <<= 1) ss += __shfl_xor(ss, o, 64);
    int wave = t >> 6, lane = t & 63;
    if (lane == 0) red[wave] = ss;
    __syncthreads();
    float tot = red[0] + red[1] + red[2] + red[3];
    float sc = rsqrtf(tot) * scalar[0];
    float v0 = x0 * sc, v1 = x1 * sc;
    v[t] = v0;
    v[t + 256] = v1;
    float sv = v0 + v1;
#pragma unroll
    for (int o = 1; o < 64; o <<= 1) sv += __shfl_xor(sv, o, 64);
    if (lane == 0) red2[wave] = sv;
    __syncthreads();
    if (t == 0) v[512] = red2[0] + red2[1] + red2[2] + red2[3];
    return;
  }
  if (bid >= 1408) {  // keysT transpose blocks
    int j = bid - 1408;  // [0,512)
    int b = j & 7;
    int tile = j >> 3;  // [0,64)
    int kt = tile & 7, dtt = tile >> 3;
    int k0 = kt * 64, d0 = dtt * 64;
    const float* kb_ = keys + ((size_t)b * 512 + k0) * 512 + d0;
    int rl = t >> 4;        // 0..15
    int cl = (t & 15) * 4;  // 0..60
#pragma unroll
    for (int p = 0; p < 4; p++) {
      float4 x =
          *reinterpret_cast<const float4*>(kb_ + (size_t)(rl + 16 * p) * 512 + cl);
      sT[cl + 0][rl + 16 * p] = (_Float16)x.x;
      sT[cl + 1][rl + 16 * p] = (_Float16)x.y;
      sT[cl + 2][rl + 16 * p] = (_Float16)x.z;
      sT[cl + 3][rl + 16 * p] = (_Float16)x.w;
    }
    __syncthreads();
    int drl = t >> 2;  // 0..63
    int drow = d0 + drl;
#pragma unroll
    for (int e = 0; e < 2; e++) {
      int kb2 = (t & 3) * 2 + e;  // local 16B block 0..7
      int bb = (k0 >> 3) + kb2;   // global k block
      int sb = swz(bb, drow);
      half8 o = *reinterpret_cast<const half8*>(&sT[drl][kb2 * 8]);
      *reinterpret_cast<half8*>(keysT + ((size_t)b * 512 + drow) * 512 + sb * 8) = o;
    }
    return;
  }
  const float* src;
  _Float16* dst;
  int r, bb = t & 63;
  if (bid < 1152) {  // A: XCD-pinned per batch
    int b = bid & 7;
    int i = bid >> 3;
    r = i * 4 + (t >> 6);  // local row [0,576)
    src = (r < 512) ? keys + ((size_t)b * 512 + r) * 512
                    : query + ((size_t)b * 64 + (r - 512)) * 512;
    dst = Acvt + ((size_t)b * 576 + r) * 512;
  } else if (bid < 1280) {
    int j = bid - 1152;
    r = j * 4 + (t >> 6);
    src = Wk + (size_t)r * 512;
    dst = Wkcvt + (size_t)r * 512;
  } else {
    int j = bid - 1280;
    r = j * 4 + (t >> 6);
    src = Wq + (size_t)r * 512;
    dst = Wqcvt + (size_t)r * 512;
  }
  int scol = swz(bb, r) * 8;
  float4 x0 = *reinterpret_cast<const float4*>(src + scol);
  float4 x1 = *reinterpret_cast<const float4*>(src + scol + 4);
  half8 o = {(_Float16)x0.x, (_Float16)x0.y, (_Float16)x0.z, (_Float16)x0.w,
             (_Float16)x1.x, (_Float16)x1.y, (_Float16)x1.z, (_Float16)x1.w};
  *reinterpret_cast<half8*>(dst + bb * 8) = o;
}

// ---------------------------------------------------------------------------
// Kernel 2: MFMA projection (unchanged from round 12). XCD-pinned.
// ---------------------------------------------------------------------------
__global__ __launch_bounds__(256) void mfma_proj_kernel(
    const _Float16* __restrict__ Acvt, const _Float16* __restrict__ Wkcvt,
    const _Float16* __restrict__ Wqcvt, const float* __restrict__ bias,
    float* __restrict__ Ek, float* __restrict__ Eq) {
  __shared__ _Float16 sA[2][64][64];
  __shared__ _Float16 sW[2][64][64];
  int lid = blockIdx.x;  // [0,576)
  int b = lid & 7;
  int rr = lid >> 3;
  int mtb = rr % 9;
  int nt = rr / 9;
  int n0 = nt * 64;
  bool isQ = (mtb == 8);
  const _Float16* Wcvt = isQ ? Wqcvt : Wkcvt;
  size_t mrowbase = (size_t)b * 576 + (size_t)mtb * 64;
  int t = threadIdx.x;
  int wave = t >> 6, lane = t & 63;
  int mw = (wave >> 1) * 32, nw = (wave & 1) * 32;
  int lr = lane & 31, g = lane >> 5;
  int arow = mw + lr, wrow = nw + lr;
  int lrow = lane >> 3, lblk = lane & 7;
  const _Float16* gAbase = Acvt + (mrowbase + wave * 16 + lrow) * 512 + lblk * 8;
  const _Float16* gWbase =
      Wcvt + ((size_t)(n0 + wave * 16 + lrow)) * 512 + lblk * 8;

  floatx16 acc;
#pragma unroll
  for (int i = 0; i < 16; i++) acc[i] = 0.f;

#define STAGE(kt, sel)                                                        \
  {                                                                           \
    int koff = (kt)*64;                                                       \
    GLD16(gAbase + koff, &sA[sel][wave * 16][0]);                             \
    GLD16(gAbase + koff + 8 * 512, &sA[sel][wave * 16 + 8][0]);               \
    GLD16(gWbase + koff, &sW[sel][wave * 16][0]);                             \
    GLD16(gWbase + koff + 8 * 512, &sW[sel][wave * 16 + 8][0]);               \
  }

  STAGE(0, 0);
  for (int kt = 0; kt < 8; kt++) {
    __syncthreads();
    if (kt < 7) STAGE(kt + 1, (kt + 1) & 1);
    int sel = kt & 1;
#pragma unroll
    for (int i = 0; i < 4; i++) {
      int ablk = (((2 * i + g) ^ arow) & 7) * 8 + ((2 * i + g) & ~7) * 8;
      int wblk = (((2 * i + g) ^ wrow) & 7) * 8 + ((2 * i + g) & ~7) * 8;
      half8 af = *reinterpret_cast<const half8*>(&sA[sel][arow][ablk]);
      half8 wf = *reinterpret_cast<const half8*>(&sW[sel][wrow][wblk]);
      acc = __builtin_amdgcn_mfma_f32_32x32x16_f16(af, wf, acc, 0, 0, 0);
    }
  }
#undef STAGE
  int col = n0 + nw + lr;
  float bv = isQ ? bias[col] : 0.f;
#pragma unroll
  for (int r = 0; r < 16; r++) {
    int lrow_out = mtb * 64 + mw + (r & 3) + 8 * (r >> 2) + 4 * g;
    float e = __builtin_amdgcn_exp2f((acc[r] + bv) * C2F);
    if (isQ)
      Eq[((size_t)b * 64 + (lrow_out - 512)) * NU_ + col] = e;
    else
      Ek[((size_t)b * 512 + lrow_out) * NU_ + col] = e;
  }
}

// ---------------------------------------------------------------------------
// Kernel 3: scores with 2-k register blocking (each thread: 2 k, 8 q, 16 u).
// NO occupancy cap (R15's (256,8) and R16's (256,4) caps forced mass VGPR
// spill: 300-450 MB scratch traffic). #pragma unroll 2 bounds the hoist
// window. One sEq read feeds 2 k-rows -> LDS bytes halved vs R14.
// S[q,k] = vtot - 2 * sum_u v[u] / (1 + Eq[q,u]*Ek[k,u])
// ---------------------------------------------------------------------------
__global__ __launch_bounds__(256) void scores_kernel(
    const float* __restrict__ Eq, const float* __restrict__ Ek,
    const float* __restrict__ v, _Float16* __restrict__ Sh) {
  __shared__ __align__(16) float sEq[8][NU_];
  __shared__ __align__(16) float sV[NU_];
  __shared__ float sRed[2][4][8][2];
  int lid = blockIdx.x;
  int b = lid & 7;
  int rrr = lid >> 3;
  int qt = rrr & 7, kt = rrr >> 3;
  int q0 = qt * 8, k0 = kt * 16;
  int t = threadIdx.x;
  const float4* eqsrc =
      reinterpret_cast<const float4*>(Eq + ((size_t)b * Q_ + q0) * NU_);
#pragma unroll
  for (int i = 0; i < 4; i++)
    reinterpret_cast<float4*>(&sEq[0][0])[t + 256 * i] = eqsrc[t + 256 * i];
  if (t < 128)
    reinterpret_cast<float4*>(sV)[t] = reinterpret_cast<const float4*>(v)[t];
  float vtot = v[512];
  __syncthreads();

  int wave = t >> 6, lane = t & 63;
  int uw = wave >> 1, kw = wave & 1;
  int klane = lane >> 4, ulane = lane & 15;
  int k = k0 + kw * 8 + klane * 2;
  const float* ekr0 = Ek + ((size_t)b * K_ + k) * NU_;
  const float* ekr1 = ekr0 + NU_;
  float acc0[8] = {}, acc1[8] = {};
#pragma unroll 2
  for (int j = 0; j < 4; j++) {
    int u = uw * 256 + ulane * 4 + 64 * j;
    float4 e0 = *reinterpret_cast<const float4*>(ekr0 + u);
    float4 e1 = *reinterpret_cast<const float4*>(ekr1 + u);
    float4 v4 = *reinterpret_cast<const float4*>(&sV[u]);
#pragma unroll
    for (int qq = 0; qq < 8; qq++) {
      float4 q4 = *reinterpret_cast<const float4*>(&sEq[qq][u]);
      // k row 0
      {
        float p0 = fmaf(q4.x, e0.x, 1.f);
        float p1 = fmaf(q4.y, e0.y, 1.f);
        float p2 = fmaf(q4.z, e0.z, 1.f);
        float p3 = fmaf(q4.w, e0.w, 1.f);
        float n01 = fmaf(v4.x, p1, v4.y * p0);
        float n23 = fmaf(v4.z, p3, v4.w * p2);
        float p01 = p0 * p1, p23 = p2 * p3;
        float num = fmaf(n01, p23, n23 * p01);
        acc0[qq] = fmaf(num, __builtin_amdgcn_rcpf(p01 * p23), acc0[qq]);
      }
      // k row 1
      {
        float p0 = fmaf(q4.x, e1.x, 1.f);
        float p1 = fmaf(q4.y, e1.y, 1.f);
        float p2 = fmaf(q4.z, e1.z, 1.f);
        float p3 = fmaf(q4.w, e1.w, 1.f);
        float n01 = fmaf(v4.x, p1, v4.y * p0);
        float n23 = fmaf(v4.z, p3, v4.w * p2);
        float p01 = p0 * p1, p23 = p2 * p3;
        float num = fmaf(n01, p23, n23 * p01);
        acc1[qq] = fmaf(num, __builtin_amdgcn_rcpf(p01 * p23), acc1[qq]);
      }
    }
  }
  // reduce over the 16 ulane lanes (bits 0..3)
#pragma unroll
  for (int qq = 0; qq < 8; qq++) {
    acc0[qq] += __shfl_xor(acc0[qq], 1, 64);
    acc0[qq] += __shfl_xor(acc0[qq], 2, 64);
    acc0[qq] += __shfl_xor(acc0[qq], 4, 64);
    acc0[qq] += __shfl_xor(acc0[qq], 8, 64);
    acc1[qq] += __shfl_xor(acc1[qq], 1, 64);
    acc1[qq] += __shfl_xor(acc1[qq], 2, 64);
    acc1[qq] += __shfl_xor(acc1[qq], 4, 64);
    acc1[qq] += __shfl_xor(acc1[qq], 8, 64);
  }
  if (uw == 1 && ulane == 0) {
#pragma unroll
    for (int qq = 0; qq < 8; qq++) {
      sRed[kw][klane][qq][0] = acc0[qq];
      sRed[kw][klane][qq][1] = acc1[qq];
    }
  }
  __syncthreads();
  if (uw == 0 && ulane == 0) {
#pragma unroll
    for (int qq = 0; qq < 8; qq++) {
      float a0 = acc0[qq] + sRed[kw][klane][qq][0];
      float a1 = acc1[qq] + sRed[kw][klane][qq][1];
      float s0 = fmaf(-2.f, a0, vtot);
      float s1 = fmaf(-2.f, a1, vtot);
      int row = q0 + qq;
      int sb = swz(k >> 3, row);
      _Float16* dst = Sh + ((size_t)b * 64 + row) * 512 + sb * 8 + (k & 7);
      dst[0] = (_Float16)s0;
      dst[1] = (_Float16)s1;
    }
  }
}

// ---------------------------------------------------------------------------
// Kernel 4: ctx via MFMA (blocks 0..63) + softmax (blocks 64..127).
// (unchanged from round 12)
// ---------------------------------------------------------------------------
__global__ __launch_bounds__(256) void ctxsm_kernel(
    const _Float16* __restrict__ Sh, const _Float16* __restrict__ keysT,
    float* __restrict__ ctx, float* __restrict__ smx) {
  __shared__ _Float16 sA[2][64][64];
  __shared__ _Float16 sW[2][64][64];
  int bid = blockIdx.x;
  int t = threadIdx.x;
  if (bid >= 64) {  // ---- softmax blocks ----
    int idx = bid - 64;
    int b = idx & 7, qt = idx >> 3;
    int q = qt * 8 + (t >> 5), lg = t & 31;
    const _Float16* srow = Sh + ((size_t)b * 64 + q) * 512;
    float sv[16];
#pragma unroll
    for (int ii = 0; ii < 16; ii++) {
      int kk = lg + ii * 32;
      int sb = swz(kk >> 3, q);
      sv[ii] = (float)srow[sb * 8 + (kk & 7)];
    }
    float m = sv[0];
#pragma unroll
    for (int ii = 1; ii < 16; ii++) m = fmaxf(m, sv[ii]);
#pragma unroll
    for (int o = 1; o < 32; o <<= 1) m = fmaxf(m, __shfl_xor(m, o, 64));
    const float L2E = 1.4426950408889634f;
    float e[16], sum = 0.f;
#pragma unroll
    for (int ii = 0; ii < 16; ii++) {
      e[ii] = __builtin_amdgcn_exp2f((sv[ii] - m) * L2E);
      sum += e[ii];
    }
#pragma unroll
    for (int o = 1; o < 32; o <<= 1) sum += __shfl_xor(sum, o, 64);
    float inv = 1.f / sum;
    float* dst = smx + ((size_t)b * 64 + q) * 512;
#pragma unroll
    for (int ii = 0; ii < 16; ii++) dst[lg + ii * 32] = e[ii] * inv;
    return;
  }
  // ---- MFMA ctx blocks ----
  int b = bid & 7, nt = bid >> 3;
  int n0 = nt * 64;
  int wave = t >> 6, lane = t & 63;
  int mw = (wave >> 1) * 32, nw = (wave & 1) * 32;
  int lr = lane & 31, g = lane >> 5;
  int arow = mw + lr, wrow = nw + lr;
  int lrow = lane >> 3, lblk = lane & 7;
  const _Float16* gAbase =
      Sh + ((size_t)b * 64 + wave * 16 + lrow) * 512 + lblk * 8;
  const _Float16* gWbase =
      keysT + ((size_t)b * 512 + n0 + wave * 16 + lrow) * 512 + lblk * 8;

  floatx16 acc;
#pragma unroll
  for (int i = 0; i < 16; i++) acc[i] = 0.f;

#define STAGE(kt, sel)                                                        \
  {                                                                           \
    int koff = (kt)*64;                                                       \
    GLD16(gAbase + koff, &sA[sel][wave * 16][0]);                             \
    GLD16(gAbase + koff + 8 * 512, &sA[sel][wave * 16 + 8][0]);               \
    GLD16(gWbase + koff, &sW[sel][wave * 16][0]);                             \
    GLD16(gWbase + koff + 8 * 512, &sW[sel][wave * 16 + 8][0]);               \
  }

  STAGE(0, 0);
  for (int kt = 0; kt < 8; kt++) {
    __syncthreads();
    if (kt < 7) STAGE(kt + 1, (kt + 1) & 1);
    int sel = kt & 1;
#pragma unroll
    for (int i = 0; i < 4; i++) {
      int ablk = (((2 * i + g) ^ arow) & 7) * 8 + ((2 * i + g) & ~7) * 8;
      int wblk = (((2 * i + g) ^ wrow) & 7) * 8 + ((2 * i + g) & ~7) * 8;
      half8 af = *reinterpret_cast<const half8*>(&sA[sel][arow][ablk]);
      half8 wf = *reinterpret_cast<const half8*>(&sW[sel][wrow][wblk]);
      acc = __builtin_amdgcn_mfma_f32_32x32x16_f16(af, wf, acc, 0, 0, 0);
    }
  }
#undef STAGE
  int col = n0 + nw + lr;
#pragma unroll
  for (int r = 0; r < 16; r++) {
    int row = mw + (r & 3) + 8 * (r >> 2) + 4 * g;
    ctx[((size_t)b * 64 + row) * 512 + col] = acc[r];
  }
}

// ---------------------------------------------------------------------------
extern "C" void kernel_launch(void* const* d_in, const int* in_sizes, int n_in,
                              void* d_out, int out_size, void* d_ws,
                              size_t ws_size, hipStream_t stream) {
  const float* query = (const float*)d_in[0];
  const float* keys = (const float*)d_in[1];
  const float* Wq = (const float*)d_in[2];
  const float* Wk = (const float*)d_in[3];
  const float* la = (const float*)d_in[4];
  const float* nscalar = (const float*)d_in[5];
  const float* nbias = (const float*)d_in[6];

  float* out = (float*)d_out;
  float* ctx = out;
  float* smx = out + (size_t)B_ * Q_ * D_;

  float* ws = (float*)d_ws;
  float* v = ws + WS_V;
  float* Eq = ws + WS_EQ;
  float* Ek = ws + WS_EK;
  _Float16* Acvt = (_Float16*)(ws + WS_FLOATS);
  _Float16* Wkcvt = Acvt + ACVT_ELEMS;
  _Float16* Wqcvt = Wkcvt + W_ELEMS;
  _Float16* keysT = Wqcvt + W_ELEMS;
  _Float16* Sh = keysT + KT_ELEMS;

  convert_kernel<<<1921, 256, 0, stream>>>(query, keys, Wq, Wk, la, nscalar,
                                           Acvt, Wkcvt, Wqcvt, keysT, v);
  mfma_proj_kernel<<<576, 256, 0, stream>>>(Acvt, Wkcvt, Wqcvt, nbias, Ek, Eq);
  scores_kernel<<<2048, 256, 0, stream>>>(Eq, Ek, v, Sh);
  ctxsm_kernel<<<128, 256, 0, stream>>>(Sh, keysT, ctx, smx);
}